// Round 1
// baseline (478.101 us; speedup 1.0000x reference)
//
#include <hip/hip_runtime.h>

#define EPS 1e-7f
#define MAX_NORM (1.0f - 1e-5f)

typedef __attribute__((ext_vector_type(8))) short bf16x8;
typedef __attribute__((ext_vector_type(4))) short short4v;
typedef __attribute__((ext_vector_type(4))) float f32x4;

__device__ __forceinline__ short f2bf(float f){
  unsigned u = __builtin_bit_cast(unsigned, f);
  u = (u + 0x7fffu + ((u >> 16) & 1u)) >> 16;
  return (short)u;
}
__device__ __forceinline__ float bf2f(short s){
  unsigned u = ((unsigned)(unsigned short)s) << 16;
  return __builtin_bit_cast(float, u);
}

// ---- setup: s = tanh(||b||) * b / ||b||, s_buf[256] = s, s_buf[256] (extra) = ||s||^2 ----
__global__ void setup_s_kernel(const float* __restrict__ b, float* __restrict__ s_buf){
  __shared__ float redv[256];
  int t = threadIdx.x;
  float v = b[t];
  redv[t] = v * v;
  __syncthreads();
  for (int off = 128; off > 0; off >>= 1){
    if (t < off) redv[t] += redv[t + off];
    __syncthreads();
  }
  float bn = sqrtf(redv[0]);
  float th = tanhf(bn);
  s_buf[t] = th * v / fmaxf(bn, EPS);
  if (t == 0) s_buf[256] = th * th;
}

// ---- setup: W fp32 [256][256] -> bf16 in B-fragment-native layout ----
// flat = (((n>>4)*8 + ks)*4 + q)*16 + (n&15))*8 + j  with k = ks*32 + q*8 + j
__global__ void conv_w_kernel(const float* __restrict__ W, short* __restrict__ WB){
  int idx = blockIdx.x * 256 + threadIdx.x;
  int n = idx >> 8, k = idx & 255;
  int ks = k >> 5, q = (k >> 3) & 3, j = k & 7;
  int dst = ((((n >> 4) * 8 + ks) * 4 + q) * 16 + (n & 15)) * 8 + j;
  WB[dst] = f2bf(W[idx]);
}

// ---- main fused kernel: 64 rows x 256 cols per workgroup ----
__global__ void hyp_main(const float* __restrict__ x, const short* __restrict__ WB,
                         const float* __restrict__ s_buf, float* __restrict__ out){
  __shared__ __align__(16) short A_lds[64 * 264];   // 64 rows x 256 k, stride 264 (+8 pad)
  __shared__ float xpart[256];
  __shared__ float redp[4][64][2];
  __shared__ float pq[64][2];

  const int tid = threadIdx.x;
  const int wave = tid >> 6, lane = tid & 63;
  const int quad = lane >> 4, l15 = lane & 15;
  const int m0 = blockIdx.x * 64;

  // stage A: fp32 global -> bf16 LDS (coalesced float4, 4KB/step per WG)
  const float4* xt = (const float4*)(x + (size_t)m0 * 256);
  #pragma unroll
  for (int i = 0; i < 16; i++){
    int f = i * 256 + tid;          // flat float4 idx in 64x64-float4 tile
    int row = f >> 6, c4 = f & 63;
    float4 v = xt[f];
    short4v p;
    p.x = f2bf(v.x); p.y = f2bf(v.y); p.z = f2bf(v.z); p.w = f2bf(v.w);
    *(short4v*)&A_lds[row * 264 + c4 * 4] = p;
  }
  __syncthreads();

  // x row-norm partials: thread t covers row t>>2, quarter t&3
  {
    int row = tid >> 2, seg = tid & 3;
    float sum = 0.f;
    #pragma unroll
    for (int i = 0; i < 8; i++){
      bf16x8 v = *(const bf16x8*)&A_lds[row * 264 + seg * 64 + i * 8];
      #pragma unroll
      for (int j = 0; j < 8; j++){ float f = bf2f(v[j]); sum += f * f; }
    }
    xpart[tid] = sum;
  }

  // MFMA K-loop: wave handles 64 rows x 64 cols (cols wave*64..), 16x16x32 tiles
  f32x4 acc[4][4];
  #pragma unroll
  for (int mt = 0; mt < 4; mt++)
    #pragma unroll
    for (int tn = 0; tn < 4; tn++) acc[mt][tn] = (f32x4){0.f, 0.f, 0.f, 0.f};

  const bf16x8* WBv = (const bf16x8*)WB;
  #pragma unroll
  for (int ks = 0; ks < 8; ks++){
    bf16x8 bfrag[4], afrag[4];
    #pragma unroll
    for (int tn = 0; tn < 4; tn++) bfrag[tn] = WBv[((wave * 4 + tn) * 8 + ks) * 64 + lane];
    #pragma unroll
    for (int mt = 0; mt < 4; mt++)
      afrag[mt] = *(const bf16x8*)&A_lds[(mt * 16 + l15) * 264 + ks * 32 + quad * 8];
    #pragma unroll
    for (int mt = 0; mt < 4; mt++)
      #pragma unroll
      for (int tn = 0; tn < 4; tn++)
        acc[mt][tn] = __builtin_amdgcn_mfma_f32_16x16x32_bf16(afrag[mt], bfrag[tn], acc[mt][tn], 0, 0, 0);
  }

  // epilogue: per-row sum(mx^2), sum(mx*s)
  float sv[4];
  #pragma unroll
  for (int tn = 0; tn < 4; tn++) sv[tn] = s_buf[wave * 64 + tn * 16 + l15];

  float msq[4][4], mds[4][4];
  #pragma unroll
  for (int mt = 0; mt < 4; mt++)
    #pragma unroll
    for (int r = 0; r < 4; r++){
      float a = 0.f, d = 0.f;
      #pragma unroll
      for (int tn = 0; tn < 4; tn++){ float c = acc[mt][tn][r]; a += c * c; d += c * sv[tn]; }
      msq[mt][r] = a; mds[mt][r] = d;
    }
  #pragma unroll
  for (int m = 1; m < 16; m <<= 1){
    #pragma unroll
    for (int mt = 0; mt < 4; mt++)
      #pragma unroll
      for (int r = 0; r < 4; r++){
        msq[mt][r] += __shfl_xor(msq[mt][r], m, 64);
        mds[mt][r] += __shfl_xor(mds[mt][r], m, 64);
      }
  }
  if (l15 == 0){
    #pragma unroll
    for (int mt = 0; mt < 4; mt++)
      #pragma unroll
      for (int r = 0; r < 4; r++){
        int row = mt * 16 + quad * 4 + r;
        redp[wave][row][0] = msq[mt][r];
        redp[wave][row][1] = mds[mt][r];
      }
  }
  __syncthreads();

  // per-row scalars P, Q (threads 0..63)
  if (tid < 64){
    int row = tid;
    float ms  = redp[0][row][0] + redp[1][row][0] + redp[2][row][0] + redp[3][row][0];
    float md  = redp[0][row][1] + redp[1][row][1] + redp[2][row][1] + redp[3][row][1];
    float xn2 = xpart[row*4+0] + xpart[row*4+1] + xpart[row*4+2] + xpart[row*4+3];
    float s2 = s_buf[256];
    float xn = fmaxf(sqrtf(xn2), EPS);
    float xc = fminf(xn, 1.0f - 1e-7f);
    float art = 0.5f * (log1pf(xc) - log1pf(-xc));
    float mxn = fmaxf(sqrtf(ms), EPS);
    float tt = tanhf(mxn / xn * art);
    float te = fminf(tt, MAX_NORM);      // proj(res): ||res|| = t
    float sr = te / mxn;                 // res = sr * mx
    float r2 = te * te;
    float xy = sr * md;                  // <res, s>
    float aa = 1.0f + 2.0f * xy + s2;
    float bc = 1.0f - r2;
    float den = fmaxf(1.0f + 2.0f * xy + r2 * s2, EPS);
    float P = aa * sr / den, Q = bc / den;
    float num2 = aa * aa * r2 + 2.0f * aa * bc * xy + bc * bc * s2;
    float on = fmaxf(sqrtf(num2) / den, EPS);
    if (on > MAX_NORM){ float fsc = MAX_NORM / on; P *= fsc; Q *= fsc; }
    pq[row][0] = P; pq[row][1] = Q;
  }
  __syncthreads();

  // store: out = P*mx + Q*s
  float* orow = out + (size_t)m0 * 256;
  #pragma unroll
  for (int mt = 0; mt < 4; mt++)
    #pragma unroll
    for (int r = 0; r < 4; r++){
      int row = mt * 16 + quad * 4 + r;
      float P = pq[row][0], Q = pq[row][1];
      #pragma unroll
      for (int tn = 0; tn < 4; tn++)
        orow[(size_t)row * 256 + wave * 64 + tn * 16 + l15] = P * acc[mt][tn][r] + Q * sv[tn];
    }
}

extern "C" void kernel_launch(void* const* d_in, const int* in_sizes, int n_in,
                              void* d_out, int out_size, void* d_ws, size_t ws_size,
                              hipStream_t stream){
  const float* x = (const float*)d_in[0];
  const float* W = (const float*)d_in[1];
  const float* b = (const float*)d_in[2];
  float* out = (float*)d_out;

  short* WB    = (short*)d_ws;                          // 256*256 bf16 = 128 KB
  float* s_buf = (float*)((char*)d_ws + 256 * 256 * 2); // 257 floats

  int N = in_sizes[0] / 256;

  setup_s_kernel<<<1, 256, 0, stream>>>(b, s_buf);
  conv_w_kernel<<<256, 256, 0, stream>>>(W, WB);
  hyp_main<<<N / 64, 256, 0, stream>>>(x, WB, s_buf, out);
}